// Round 3
// baseline (416.592 us; speedup 1.0000x reference)
//
#include <hip/hip_runtime.h>
#include <hip/hip_bf16.h>
#include <stdint.h>
#include <cmath>

using bf16 = __hip_bfloat16;
typedef __attribute__((ext_vector_type(8))) short bf16x8;
typedef __attribute__((ext_vector_type(4))) float f32x4;

#define MFMA16(a, b, c) __builtin_amdgcn_mfma_f32_16x16x32_bf16(a, b, c, 0, 0, 0)

#define NEG_BIG (-1e30f)

// async global->LDS, 16B per lane. LDS dest = wave-uniform base + lane*16.
__device__ __forceinline__ void async_ld16(const bf16* g, bf16* l) {
  __builtin_amdgcn_global_load_lds(
      (const __attribute__((address_space(1))) unsigned int*)g,
      (__attribute__((address_space(3))) unsigned int*)l, 16, 0, 0);
}

template <typename T> __device__ __forceinline__ T cvt_out(float v);
template <> __device__ __forceinline__ float cvt_out<float>(float v) { return v; }
template <> __device__ __forceinline__ bf16 cvt_out<bf16>(float v) { return __float2bfloat16(v); }

// ---------------------------------------------------------------------------
// f32 -> bf16 convert (vectorized, 4 elems/thread)
// ---------------------------------------------------------------------------
__global__ void convert_f32_bf16(const float* __restrict__ in, bf16* __restrict__ out, int n4) {
  const int i = blockIdx.x * blockDim.x + threadIdx.x;
  if (i < n4) {
    const float4 v = ((const float4*)in)[i];
    bf16 o[4] = {__float2bfloat16(v.x), __float2bfloat16(v.y),
                 __float2bfloat16(v.z), __float2bfloat16(v.w)};
    *(uint64_t*)&out[i * 4] = *(const uint64_t*)o;
  }
}

// ---------------------------------------------------------------------------
// f32 in (R x Cc) -> bf16 out (Cc x R) transpose
// ---------------------------------------------------------------------------
__global__ void transpose_f32_bf16(const float* __restrict__ in, bf16* __restrict__ out,
                                   int R, int Cc) {
  __shared__ bf16 tile[32][33];
  const int c0 = blockIdx.x * 32, r0 = blockIdx.y * 32;
  const int x = threadIdx.x & 31;
  const int y = threadIdx.x >> 5;  // 0..7
#pragma unroll
  for (int yy = y; yy < 32; yy += 8)
    tile[yy][x] = __float2bfloat16(in[(size_t)(r0 + yy) * Cc + c0 + x]);
  __syncthreads();
#pragma unroll
  for (int yy = y; yy < 32; yy += 8)
    out[(size_t)(c0 + yy) * R + r0 + x] = tile[x][yy];
}

// ---------------------------------------------------------------------------
// GEMM-BT: C[m][n] = sum_k A[m][k] * B[n][k].  A: MxK, B: NxK row-major bf16.
// 128x128 tile, BK=32, 256 threads (4 waves, each 64x64 as 4x4 MFMA tiles).
// MODE 0: C row-major MxN (output type OT)
// MODE 1: C -> (b,h,n,d):  idx = ((b*16+h)*2048 + n)*128 + d
// MODE 2: C -> (b,h,d,n):  idx = ((b*16+h)*128 + d)*2048 + n
// ---------------------------------------------------------------------------
template <int MODE, typename OT>
__global__ __launch_bounds__(256)
void gemm_bt(const bf16* __restrict__ A, const bf16* __restrict__ B,
             OT* __restrict__ C, int M, int N, int K) {
  __shared__ __align__(16) bf16 As[128 * 32];
  __shared__ __align__(16) bf16 Bs[128 * 32];
  const int t = threadIdx.x;
  const int l = t & 63;
  const int w = t >> 6;
  const int q4 = l >> 4;    // quad 0..3
  const int li = l & 15;
  const int m0 = blockIdx.y * 128;
  const int n0 = blockIdx.x * 128;
  const int wr = (w >> 1) * 64;
  const int wc = (w & 1) * 64;

  f32x4 acc[4][4] = {};

  const int colst = (t & 3) * 8;  // staging col within 32-wide tile
  const bf16* gA = A + (size_t)m0 * K;
  const bf16* gB = B + (size_t)n0 * K;

  for (int k0 = 0; k0 < K; k0 += 32) {
#pragma unroll
    for (int p = 0; p < 2; ++p) {
      const int row = p * 64 + (t >> 2);
      const int lbase = p * 2048 + (t & ~63) * 8;
      async_ld16(gA + (size_t)row * K + k0 + colst, &As[lbase]);
      async_ld16(gB + (size_t)row * K + k0 + colst, &Bs[lbase]);
    }
    __syncthreads();
    bf16x8 af[4], bfr[4];
#pragma unroll
    for (int i = 0; i < 4; ++i)
      af[i] = *(const bf16x8*)&As[(wr + i * 16 + li) * 32 + q4 * 8];
#pragma unroll
    for (int j = 0; j < 4; ++j)
      bfr[j] = *(const bf16x8*)&Bs[(wc + j * 16 + li) * 32 + q4 * 8];
#pragma unroll
    for (int i = 0; i < 4; ++i)
#pragma unroll
      for (int j = 0; j < 4; ++j)
        acc[i][j] = MFMA16(af[i], bfr[j], acc[i][j]);
    __syncthreads();
  }

  // epilogue: C/D layout col=li, row=q4*4+r (verified m89/m91)
#pragma unroll
  for (int i = 0; i < 4; ++i) {
#pragma unroll
    for (int j = 0; j < 4; ++j) {
#pragma unroll
      for (int r = 0; r < 4; ++r) {
        const int gm = m0 + wr + i * 16 + q4 * 4 + r;
        const int gn = n0 + wc + j * 16 + li;
        const float v = acc[i][j][r];
        if (MODE == 0) {
          C[(size_t)gm * N + gn] = cvt_out<OT>(v);
        } else if (MODE == 1) {
          const int b = gm >> 11, nn = gm & 2047;
          const int h = gn >> 7, d = gn & 127;
          C[((size_t)(b * 16 + h) * 2048 + nn) * 128 + d] = cvt_out<OT>(v);
        } else {
          const int h = gm >> 7, d = gm & 127;
          const int b = gn >> 11, nn = gn & 2047;
          C[((size_t)(b * 16 + h) * 128 + d) * 2048 + nn] = cvt_out<OT>(v);
        }
      }
    }
  }
}

// ---------------------------------------------------------------------------
// Causal flash attention.
// qm,km: (BH=32, N=2048, 128) bf16; vtm: (BH, 128, 2048) bf16 (V transposed)
// om: (4096, 2048) = (b*2048+n, h*128+d) bf16
// Block: 256 thr (4 waves); 64 Q rows/block (16 per wave); KT=64; scale 1/8.
// ---------------------------------------------------------------------------
#define KSTR 136
#define VSTR 72

__global__ __launch_bounds__(256)
void flash_attn(const bf16* __restrict__ qm, const bf16* __restrict__ km,
                const bf16* __restrict__ vtm, bf16* __restrict__ om) {
  __shared__ __align__(16) bf16 Ks[64 * KSTR];
  __shared__ __align__(16) bf16 Vts[128 * VSTR];
  __shared__ __align__(16) bf16 Ps[4][16 * 72];  // per-wave P, padded stride 72

  const int t = threadIdx.x;
  const int l = t & 63, w = t >> 6;
  const int q4 = l >> 4, li = l & 15;
  const int qt = blockIdx.x, bh = blockIdx.y;
  const int qs = qt * 64;
  const size_t qkbase = (size_t)bh * 2048 * 128;
  const size_t vbase = (size_t)bh * 128 * 2048;

  // Q fragments (A operand): lane holds Q[qs+w*16+li][f*32 + q4*8 + j]
  bf16x8 qf[4];
  const bf16* Qb = qm + qkbase + (size_t)(qs + w * 16) * 128;
#pragma unroll
  for (int f = 0; f < 4; ++f)
    qf[f] = *(const bf16x8*)(Qb + (size_t)li * 128 + f * 32 + q4 * 8);

  f32x4 O[8] = {};
  float mst[4], lst[4];
#pragma unroll
  for (int r = 0; r < 4; ++r) { mst[r] = NEG_BIG; lst[r] = 0.f; }

  for (int kt = 0; kt <= qt; ++kt) {
    const int kn = kt * 64;
    // stage K (64x128) and Vt (128x64) tiles, same-type bf16x8 stores
#pragma unroll
    for (int p = 0; p < 4; ++p) {
      const int L = p * 256 + t;  // 0..1023
      {
        const int row = L >> 4, c = L & 15;
        *(bf16x8*)&Ks[row * KSTR + c * 8] =
            *(const bf16x8*)(km + qkbase + (size_t)(kn + row) * 128 + c * 8);
      }
      {
        const int row = L >> 3, c = L & 7;
        *(bf16x8*)&Vts[row * VSTR + c * 8] =
            *(const bf16x8*)(vtm + vbase + (size_t)row * 2048 + kn + c * 8);
      }
    }
    __syncthreads();

    // S = Q K^T (per wave: 16 x 64)
    f32x4 S[4];
#pragma unroll
    for (int j = 0; j < 4; ++j) {
      f32x4 s = {0.f, 0.f, 0.f, 0.f};
#pragma unroll
      for (int f = 0; f < 4; ++f) {
        const bf16x8 kf = *(const bf16x8*)&Ks[(j * 16 + li) * KSTR + (f * 4 + q4) * 8];
        s = MFMA16(qf[f], kf, s);
      }
      S[j] = s;
    }

    // online softmax (rows owned by 16-lane groups; row = q4*4+r, col = li)
    const bool diag = (kt == qt);
    float p[4][4];
#pragma unroll
    for (int r = 0; r < 4; ++r) {
      float mx = NEG_BIG;
#pragma unroll
      for (int j = 0; j < 4; ++j) {
        float sv = S[j][r] * 0.125f;
        if (diag) {
          const int gn = kn + j * 16 + li;
          const int gm = qs + w * 16 + q4 * 4 + r;
          if (gn > gm) sv = NEG_BIG;
        }
        p[j][r] = sv;
        mx = fmaxf(mx, sv);
      }
#pragma unroll
      for (int off = 1; off < 16; off <<= 1)
        mx = fmaxf(mx, __shfl_xor(mx, off, 16));
      const float nm = fmaxf(mst[r], mx);
      const float alpha = __expf(mst[r] - nm);
      mst[r] = nm;
      float rs = 0.f;
#pragma unroll
      for (int j = 0; j < 4; ++j) {
        const float e = __expf(p[j][r] - nm);
        p[j][r] = e;
        rs += e;
      }
#pragma unroll
      for (int off = 1; off < 16; off <<= 1)
        rs += __shfl_xor(rs, off, 16);
      lst[r] = lst[r] * alpha + rs;
#pragma unroll
      for (int dt = 0; dt < 8; ++dt) O[dt][r] *= alpha;
      // P (C-layout) -> per-wave LDS (row-major, padded stride 72)
#pragma unroll
      for (int j = 0; j < 4; ++j)
        Ps[w][(q4 * 4 + r) * 72 + j * 16 + li] = __float2bfloat16(p[j][r]);
    }

    // Drain DS queue + compiler barrier before re-reading Ps as vectors.
    __asm__ volatile("s_waitcnt lgkmcnt(0)" ::: "memory");

    // O += P V  (P A-frags from Ps; Vt B-frags from padded Vts)
    bf16x8 pa[2];
#pragma unroll
    for (int f = 0; f < 2; ++f)
      pa[f] = *(const bf16x8*)&Ps[w][li * 72 + f * 32 + q4 * 8];
#pragma unroll
    for (int dt = 0; dt < 8; ++dt) {
#pragma unroll
      for (int f = 0; f < 2; ++f) {
        const bf16x8 vb = *(const bf16x8*)&Vts[(dt * 16 + li) * VSTR + (f * 4 + q4) * 8];
        O[dt] = MFMA16(pa[f], vb, O[dt]);
      }
    }
    __syncthreads();
  }

  // epilogue: normalize and write (b*2048+n, h*128+d)
  const int b = bh >> 4, h = bh & 15;
  const size_t obase = (size_t)(b * 2048 + qs + w * 16) * 2048 + h * 128;
#pragma unroll
  for (int r = 0; r < 4; ++r) {
    const float inv = 1.0f / lst[r];
#pragma unroll
    for (int dt = 0; dt < 8; ++dt)
      om[obase + (size_t)(q4 * 4 + r) * 2048 + dt * 16 + li] =
          __float2bfloat16(O[dt][r] * inv);
  }
}

// ---------------------------------------------------------------------------
extern "C" void kernel_launch(void* const* d_in, const int* in_sizes, int n_in,
                              void* d_out, int out_size, void* d_ws, size_t ws_size,
                              hipStream_t stream) {
  // Reference dtypes are float32 (inputs AND output).
  const float* x = (const float*)d_in[0];
  const float* Wq = (const float*)d_in[1];
  const float* Wk = (const float*)d_in[2];
  const float* Wv = (const float*)d_in[3];
  const float* Wo = (const float*)d_in[4];
  float* out = (float*)d_out;

  bf16* ws = (bf16*)d_ws;
  bf16* xb = ws;                          // 4M elems: x in bf16 (4096 x 1024)
  bf16* wT = xb + (1u << 22);             // 2M elems: transposed weight (reused)
  bf16* q_ws = wT + (1u << 21);           // 8M elems: (b,h,n,128)
  bf16* k_ws = q_ws + (1u << 23);         // 8M elems: (b,h,n,128)
  bf16* vt_ws = k_ws + (1u << 23);        // 8M elems: (b,h,128,n)
  bf16* at_ws = vt_ws + (1u << 23);       // 8M elems: (4096, 2048)
  // total: 38M elems = 76 MB

  const dim3 blk(256);

  // x -> bf16  (4096*1024 = 2^22 elems, 4/thread)
  convert_f32_bf16<<<dim3(4096), blk, 0, stream>>>(x, xb, 1 << 20);

  // Q = x @ Wq  -> (b,h,n,d)
  transpose_f32_bf16<<<dim3(64, 32), blk, 0, stream>>>(Wq, wT, 1024, 2048);
  gemm_bt<1, bf16><<<dim3(16, 32), blk, 0, stream>>>(xb, wT, q_ws, 4096, 2048, 1024);
  // K = x @ Wk  -> (b,h,n,d)
  transpose_f32_bf16<<<dim3(64, 32), blk, 0, stream>>>(Wk, wT, 1024, 2048);
  gemm_bt<1, bf16><<<dim3(16, 32), blk, 0, stream>>>(xb, wT, k_ws, 4096, 2048, 1024);
  // V^T = WvT @ x^T -> (b,h,d,n)
  transpose_f32_bf16<<<dim3(64, 32), blk, 0, stream>>>(Wv, wT, 1024, 2048);
  gemm_bt<2, bf16><<<dim3(32, 16), blk, 0, stream>>>(wT, xb, vt_ws, 2048, 4096, 1024);
  // attention
  flash_attn<<<dim3(32, 32), blk, 0, stream>>>(q_ws, k_ws, vt_ws, at_ws);
  // out = attn @ Wo  (f32 output)
  transpose_f32_bf16<<<dim3(32, 64), blk, 0, stream>>>(Wo, wT, 2048, 1024);
  gemm_bt<0, float><<<dim3(8, 32), blk, 0, stream>>>(at_ws, wT, out, 4096, 1024, 2048);
}

// Round 4
// 387.213 us; speedup vs baseline: 1.0759x; 1.0759x over previous
//
#include <hip/hip_runtime.h>
#include <hip/hip_bf16.h>
#include <stdint.h>
#include <cmath>

using bf16 = __hip_bfloat16;
typedef __attribute__((ext_vector_type(8))) short bf16x8;
typedef __attribute__((ext_vector_type(4))) float f32x4;

#define MFMA16(a, b, c) __builtin_amdgcn_mfma_f32_16x16x32_bf16(a, b, c, 0, 0, 0)

#define NEG_BIG (-1e30f)

// async global->LDS, 16B per lane. LDS dest = wave-uniform base + lane*16.
__device__ __forceinline__ void async_ld16(const bf16* g, bf16* l) {
  __builtin_amdgcn_global_load_lds(
      (const __attribute__((address_space(1))) unsigned int*)g,
      (__attribute__((address_space(3))) unsigned int*)l, 16, 0, 0);
}

template <typename T> __device__ __forceinline__ T cvt_out(float v);
template <> __device__ __forceinline__ float cvt_out<float>(float v) { return v; }
template <> __device__ __forceinline__ bf16 cvt_out<bf16>(float v) { return __float2bfloat16(v); }

// ---------------------------------------------------------------------------
// f32 -> bf16 convert (vectorized, 4 elems/thread)
// ---------------------------------------------------------------------------
__global__ void convert_f32_bf16(const float* __restrict__ in, bf16* __restrict__ out, int n4) {
  const int i = blockIdx.x * blockDim.x + threadIdx.x;
  if (i < n4) {
    const float4 v = ((const float4*)in)[i];
    bf16 o[4] = {__float2bfloat16(v.x), __float2bfloat16(v.y),
                 __float2bfloat16(v.z), __float2bfloat16(v.w)};
    *(uint64_t*)&out[i * 4] = *(const uint64_t*)o;
  }
}

// ---------------------------------------------------------------------------
// f32 in (R x Cc) -> bf16 out (Cc x R) transpose
// ---------------------------------------------------------------------------
__global__ void transpose_f32_bf16(const float* __restrict__ in, bf16* __restrict__ out,
                                   int R, int Cc) {
  __shared__ bf16 tile[32][33];
  const int c0 = blockIdx.x * 32, r0 = blockIdx.y * 32;
  const int x = threadIdx.x & 31;
  const int y = threadIdx.x >> 5;  // 0..7
#pragma unroll
  for (int yy = y; yy < 32; yy += 8)
    tile[yy][x] = __float2bfloat16(in[(size_t)(r0 + yy) * Cc + c0 + x]);
  __syncthreads();
#pragma unroll
  for (int yy = y; yy < 32; yy += 8)
    out[(size_t)(c0 + yy) * R + r0 + x] = tile[x][yy];
}

// ---------------------------------------------------------------------------
// GEMM-BT: C[m][n] = sum_k A[m][k] * B[n][k].  A: MxK, B: NxK row-major bf16.
// 128x128 tile, BK=32, 256 threads (4 waves, each 64x64 as 4x4 MFMA tiles).
// MODE 0: C row-major MxN (output type OT)
// MODE 1: C -> (b,h,n,d):  idx = ((b*16+h)*2048 + n)*128 + d
// MODE 2: C -> (b,h,d,n):  idx = ((b*16+h)*128 + d)*2048 + n
// ---------------------------------------------------------------------------
template <int MODE, typename OT>
__global__ __launch_bounds__(256)
void gemm_bt(const bf16* __restrict__ A, const bf16* __restrict__ B,
             OT* __restrict__ C, int M, int N, int K) {
  __shared__ __align__(16) bf16 As[128 * 32];
  __shared__ __align__(16) bf16 Bs[128 * 32];
  const int t = threadIdx.x;
  const int l = t & 63;
  const int w = t >> 6;
  const int q4 = l >> 4;    // quad 0..3
  const int li = l & 15;
  const int m0 = blockIdx.y * 128;
  const int n0 = blockIdx.x * 128;
  const int wr = (w >> 1) * 64;
  const int wc = (w & 1) * 64;

  f32x4 acc[4][4] = {};

  const int colst = (t & 3) * 8;  // staging col within 32-wide tile
  const bf16* gA = A + (size_t)m0 * K;
  const bf16* gB = B + (size_t)n0 * K;

  for (int k0 = 0; k0 < K; k0 += 32) {
#pragma unroll
    for (int p = 0; p < 2; ++p) {
      const int row = p * 64 + (t >> 2);
      const int lbase = p * 2048 + (t & ~63) * 8;
      async_ld16(gA + (size_t)row * K + k0 + colst, &As[lbase]);
      async_ld16(gB + (size_t)row * K + k0 + colst, &Bs[lbase]);
    }
    __syncthreads();
    bf16x8 af[4], bfr[4];
#pragma unroll
    for (int i = 0; i < 4; ++i)
      af[i] = *(const bf16x8*)&As[(wr + i * 16 + li) * 32 + q4 * 8];
#pragma unroll
    for (int j = 0; j < 4; ++j)
      bfr[j] = *(const bf16x8*)&Bs[(wc + j * 16 + li) * 32 + q4 * 8];
#pragma unroll
    for (int i = 0; i < 4; ++i)
#pragma unroll
      for (int j = 0; j < 4; ++j)
        acc[i][j] = MFMA16(af[i], bfr[j], acc[i][j]);
    __syncthreads();
  }

  // epilogue: C/D layout col=li, row=q4*4+r (verified m89/m91)
#pragma unroll
  for (int i = 0; i < 4; ++i) {
#pragma unroll
    for (int j = 0; j < 4; ++j) {
#pragma unroll
      for (int r = 0; r < 4; ++r) {
        const int gm = m0 + wr + i * 16 + q4 * 4 + r;
        const int gn = n0 + wc + j * 16 + li;
        const float v = acc[i][j][r];
        if (MODE == 0) {
          C[(size_t)gm * N + gn] = cvt_out<OT>(v);
        } else if (MODE == 1) {
          const int b = gm >> 11, nn = gm & 2047;
          const int h = gn >> 7, d = gn & 127;
          C[((size_t)(b * 16 + h) * 2048 + nn) * 128 + d] = cvt_out<OT>(v);
        } else {
          const int h = gm >> 7, d = gm & 127;
          const int b = gn >> 11, nn = gn & 2047;
          C[((size_t)(b * 16 + h) * 128 + d) * 2048 + nn] = cvt_out<OT>(v);
        }
      }
    }
  }
}

// ---------------------------------------------------------------------------
// Causal flash attention with paired q-tiles for load balance.
// qm,km: (BH=32, N=2048, 128) bf16; vtm: (BH, 128, 2048) bf16 (V transposed)
// om: (4096, 2048) = (b*2048+n, h*128+d) bf16
// Block: 256 thr (4 waves); 64 Q rows per pass (16/wave); KT=64; scale 1/8.
// Each block runs q-tile blockIdx.x then q-tile 31-blockIdx.x: constant 33
// K-tiles of work per block -> balanced grid of 512 blocks (2/CU).
// Ks: unpadded stride 128, XOR chunk swizzle (phys chunk = c ^ (row&7));
// Vts: padded stride 72 (read pattern 2-way aliased = free).
// ---------------------------------------------------------------------------
#define VSTR 72

__global__ __launch_bounds__(256)
void flash_attn(const bf16* __restrict__ qm, const bf16* __restrict__ km,
                const bf16* __restrict__ vtm, bf16* __restrict__ om) {
  __shared__ __align__(16) bf16 Ks[64 * 128];
  __shared__ __align__(16) bf16 Vts[128 * VSTR];
  __shared__ __align__(16) bf16 Ps[4][16 * 72];  // per-wave P, padded stride 72

  const int t = threadIdx.x;
  const int l = t & 63, w = t >> 6;
  const int q4 = l >> 4, li = l & 15;
  const int bh = blockIdx.y;
  const size_t qkbase = (size_t)bh * 2048 * 128;
  const size_t vbase = (size_t)bh * 128 * 2048;
  const int b = bh >> 4, h = bh & 15;

  for (int pass = 0; pass < 2; ++pass) {
    const int qt = pass == 0 ? (int)blockIdx.x : 31 - (int)blockIdx.x;
    const int qs = qt * 64;

    // Q fragments (A operand): lane holds Q[qs+w*16+li][f*32 + q4*8 + j]
    bf16x8 qf[4];
    const bf16* Qb = qm + qkbase + (size_t)(qs + w * 16) * 128;
#pragma unroll
    for (int f = 0; f < 4; ++f)
      qf[f] = *(const bf16x8*)(Qb + (size_t)li * 128 + f * 32 + q4 * 8);

    f32x4 O[8] = {};
    float mst[4], lst[4];
#pragma unroll
    for (int r = 0; r < 4; ++r) { mst[r] = NEG_BIG; lst[r] = 0.f; }

    for (int kt = 0; kt <= qt; ++kt) {
      const int kn = kt * 64;
      // stage K (64x128, XOR-swizzled chunks) and Vt (128x64, padded)
#pragma unroll
      for (int p = 0; p < 4; ++p) {
        const int L = p * 256 + t;  // 0..1023
        {
          const int row = L >> 4, c = L & 15;
          *(bf16x8*)&Ks[row * 128 + ((c ^ (row & 7)) * 8)] =
              *(const bf16x8*)(km + qkbase + (size_t)(kn + row) * 128 + c * 8);
        }
        {
          const int row = L >> 3, c = L & 7;
          *(bf16x8*)&Vts[row * VSTR + c * 8] =
              *(const bf16x8*)(vtm + vbase + (size_t)row * 2048 + kn + c * 8);
        }
      }
      __syncthreads();

      // S = Q K^T (per wave: 16 x 64)
      f32x4 S[4];
#pragma unroll
      for (int j = 0; j < 4; ++j) {
        f32x4 s = {0.f, 0.f, 0.f, 0.f};
#pragma unroll
        for (int f = 0; f < 4; ++f) {
          const bf16x8 kf =
              *(const bf16x8*)&Ks[(j * 16 + li) * 128 + (((f * 4 + q4) ^ (li & 7)) * 8)];
          s = MFMA16(qf[f], kf, s);
        }
        S[j] = s;
      }

      // online softmax (rows owned by 16-lane groups; row = q4*4+r, col = li)
      const bool diag = (kt == qt);
      float p[4][4];
#pragma unroll
      for (int r = 0; r < 4; ++r) {
        float mx = NEG_BIG;
#pragma unroll
        for (int j = 0; j < 4; ++j) {
          float sv = S[j][r] * 0.125f;
          if (diag) {
            const int gn = kn + j * 16 + li;
            const int gm = qs + w * 16 + q4 * 4 + r;
            if (gn > gm) sv = NEG_BIG;
          }
          p[j][r] = sv;
          mx = fmaxf(mx, sv);
        }
#pragma unroll
        for (int off = 1; off < 16; off <<= 1)
          mx = fmaxf(mx, __shfl_xor(mx, off, 16));
        const float nm = fmaxf(mst[r], mx);
        const float alpha = __expf(mst[r] - nm);
        mst[r] = nm;
        float rs = 0.f;
#pragma unroll
        for (int j = 0; j < 4; ++j) {
          const float e = __expf(p[j][r] - nm);
          p[j][r] = e;
          rs += e;
        }
#pragma unroll
        for (int off = 1; off < 16; off <<= 1)
          rs += __shfl_xor(rs, off, 16);
        lst[r] = lst[r] * alpha + rs;
#pragma unroll
        for (int dt = 0; dt < 8; ++dt) O[dt][r] *= alpha;
        // P (C-layout) -> per-wave LDS (row-major, padded stride 72)
#pragma unroll
        for (int j = 0; j < 4; ++j)
          Ps[w][(q4 * 4 + r) * 72 + j * 16 + li] = __float2bfloat16(p[j][r]);
      }

      // Drain DS queue + compiler barrier before re-reading Ps as vectors.
      __asm__ volatile("s_waitcnt lgkmcnt(0)" ::: "memory");

      // O += P V  (P A-frags from Ps; Vt B-frags from padded Vts)
      bf16x8 pa[2];
#pragma unroll
      for (int f = 0; f < 2; ++f)
        pa[f] = *(const bf16x8*)&Ps[w][li * 72 + f * 32 + q4 * 8];
#pragma unroll
      for (int dt = 0; dt < 8; ++dt) {
#pragma unroll
        for (int f = 0; f < 2; ++f) {
          const bf16x8 vb =
              *(const bf16x8*)&Vts[(dt * 16 + li) * VSTR + (f * 4 + q4) * 8];
          O[dt] = MFMA16(pa[f], vb, O[dt]);
        }
      }
      __syncthreads();
    }

    // epilogue: normalize and write (b*2048+n, h*128+d)
    const size_t obase = (size_t)(b * 2048 + qs + w * 16) * 2048 + h * 128;
#pragma unroll
    for (int r = 0; r < 4; ++r) {
      const float inv = 1.0f / lst[r];
#pragma unroll
      for (int dt = 0; dt < 8; ++dt)
        om[obase + (size_t)(q4 * 4 + r) * 2048 + dt * 16 + li] =
            __float2bfloat16(O[dt][r] * inv);
    }
  }
}

// ---------------------------------------------------------------------------
extern "C" void kernel_launch(void* const* d_in, const int* in_sizes, int n_in,
                              void* d_out, int out_size, void* d_ws, size_t ws_size,
                              hipStream_t stream) {
  // Reference dtypes are float32 (inputs AND output).
  const float* x = (const float*)d_in[0];
  const float* Wq = (const float*)d_in[1];
  const float* Wk = (const float*)d_in[2];
  const float* Wv = (const float*)d_in[3];
  const float* Wo = (const float*)d_in[4];
  float* out = (float*)d_out;

  bf16* ws = (bf16*)d_ws;
  bf16* xb = ws;                          // 4M elems: x in bf16 (4096 x 1024)
  bf16* wT = xb + (1u << 22);             // 2M elems: transposed weight (reused)
  bf16* q_ws = wT + (1u << 21);           // 8M elems: (b,h,n,128)
  bf16* k_ws = q_ws + (1u << 23);         // 8M elems: (b,h,n,128)
  bf16* vt_ws = k_ws + (1u << 23);        // 8M elems: (b,h,128,n)
  bf16* at_ws = vt_ws + (1u << 23);       // 8M elems: (4096, 2048)
  // total: 38M elems = 76 MB

  const dim3 blk(256);

  // x -> bf16  (4096*1024 = 2^22 elems, 4/thread)
  convert_f32_bf16<<<dim3(4096), blk, 0, stream>>>(x, xb, 1 << 20);

  // Q = x @ Wq  -> (b,h,n,d)
  transpose_f32_bf16<<<dim3(64, 32), blk, 0, stream>>>(Wq, wT, 1024, 2048);
  gemm_bt<1, bf16><<<dim3(16, 32), blk, 0, stream>>>(xb, wT, q_ws, 4096, 2048, 1024);
  // K = x @ Wk  -> (b,h,n,d)
  transpose_f32_bf16<<<dim3(64, 32), blk, 0, stream>>>(Wk, wT, 1024, 2048);
  gemm_bt<1, bf16><<<dim3(16, 32), blk, 0, stream>>>(xb, wT, k_ws, 4096, 2048, 1024);
  // V^T = WvT @ x^T -> (b,h,d,n)
  transpose_f32_bf16<<<dim3(64, 32), blk, 0, stream>>>(Wv, wT, 1024, 2048);
  gemm_bt<2, bf16><<<dim3(32, 16), blk, 0, stream>>>(wT, xb, vt_ws, 2048, 4096, 1024);
  // attention (paired causal tiles: grid.x = 16, each block does qt and 31-qt)
  flash_attn<<<dim3(16, 32), blk, 0, stream>>>(q_ws, k_ws, vt_ws, at_ws);
  // out = attn @ Wo  (f32 output)
  transpose_f32_bf16<<<dim3(32, 64), blk, 0, stream>>>(Wo, wT, 2048, 1024);
  gemm_bt<0, float><<<dim3(8, 32), blk, 0, stream>>>(at_ws, wT, out, 4096, 1024, 2048);
}

// Round 5
// 313.799 us; speedup vs baseline: 1.3276x; 1.2340x over previous
//
#include <hip/hip_runtime.h>
#include <hip/hip_bf16.h>
#include <stdint.h>
#include <cmath>

using bf16 = __hip_bfloat16;
typedef __attribute__((ext_vector_type(8))) short bf16x8;
typedef __attribute__((ext_vector_type(4))) short bf16x4;
typedef __attribute__((ext_vector_type(4))) float f32x4;

#define MFMA16(a, b, c) __builtin_amdgcn_mfma_f32_16x16x32_bf16(a, b, c, 0, 0, 0)

#if defined(__has_builtin)
#if __has_builtin(__builtin_amdgcn_mfma_f32_16x16x16bf16_1k)
#define HAVE_MFMA_K16 1
#endif
#endif

#define NEG_BIG (-1e30f)

__device__ __forceinline__ short f2bf(float v) {
  return __builtin_bit_cast(short, __float2bfloat16(v));
}

// async global->LDS, 16B per lane. LDS dest = wave-uniform base + lane*16.
__device__ __forceinline__ void async_ld16(const bf16* g, bf16* l) {
  __builtin_amdgcn_global_load_lds(
      (const __attribute__((address_space(1))) unsigned int*)g,
      (__attribute__((address_space(3))) unsigned int*)l, 16, 0, 0);
}

template <typename T> __device__ __forceinline__ T cvt_out(float v);
template <> __device__ __forceinline__ float cvt_out<float>(float v) { return v; }
template <> __device__ __forceinline__ bf16 cvt_out<bf16>(float v) { return __float2bfloat16(v); }

// ---------------------------------------------------------------------------
// f32 -> bf16 convert (vectorized, 4 elems/thread)
// ---------------------------------------------------------------------------
__global__ void convert_f32_bf16(const float* __restrict__ in, bf16* __restrict__ out, int n4) {
  const int i = blockIdx.x * blockDim.x + threadIdx.x;
  if (i < n4) {
    const float4 v = ((const float4*)in)[i];
    bf16 o[4] = {__float2bfloat16(v.x), __float2bfloat16(v.y),
                 __float2bfloat16(v.z), __float2bfloat16(v.w)};
    *(uint64_t*)&out[i * 4] = *(const uint64_t*)o;
  }
}

// ---------------------------------------------------------------------------
// All four weight transposes (f32 in -> bf16 out, transposed) in one dispatch.
// z<3: Wq/Wk/Wv (1024 x 2048); z==3: Wo (2048 x 1024).
// ---------------------------------------------------------------------------
__global__ void transpose4_f32_bf16(const float* __restrict__ Wq, const float* __restrict__ Wk,
                                    const float* __restrict__ Wv, const float* __restrict__ Wo,
                                    bf16* __restrict__ tq, bf16* __restrict__ tk,
                                    bf16* __restrict__ tv, bf16* __restrict__ to_) {
  __shared__ bf16 tile[32][33];
  const int z = blockIdx.z;
  const float* in = z == 0 ? Wq : z == 1 ? Wk : z == 2 ? Wv : Wo;
  bf16* out = z == 0 ? tq : z == 1 ? tk : z == 2 ? tv : to_;
  int R, Cc, c0, r0;
  if (z < 3) {
    R = 1024; Cc = 2048; c0 = blockIdx.x * 32; r0 = blockIdx.y * 32;
  } else {
    R = 2048; Cc = 1024;
    const int tt = blockIdx.y * 64 + blockIdx.x;
    c0 = (tt & 31) * 32; r0 = (tt >> 5) * 32;
  }
  const int x = threadIdx.x & 31;
  const int y = threadIdx.x >> 5;
#pragma unroll
  for (int yy = y; yy < 32; yy += 8)
    tile[yy][x] = __float2bfloat16(in[(size_t)(r0 + yy) * Cc + c0 + x]);
  __syncthreads();
#pragma unroll
  for (int yy = y; yy < 32; yy += 8)
    out[(size_t)(c0 + yy) * R + r0 + x] = tile[x][yy];
}

// ---------------------------------------------------------------------------
// GEMM-BT: C[m][n] = sum_k A[m][k] * B[n][k].  A: MxK, B: NxK row-major bf16.
// 128x128 tile, BK=32, 256 threads (4 waves, each 64x64 as 4x4 MFMA tiles).
// MODE 0: C row-major MxN (output type OT)
// MODE 1: C -> (b,h,n,d):  idx = ((b*16+h)*2048 + n)*128 + d
// MODE 2: C -> (b,h,d,n):  idx = ((b*16+h)*128 + d)*2048 + n
// ---------------------------------------------------------------------------
template <int MODE, typename OT>
__global__ __launch_bounds__(256)
void gemm_bt(const bf16* __restrict__ A, const bf16* __restrict__ B,
             OT* __restrict__ C, int M, int N, int K) {
  __shared__ __align__(16) bf16 As[128 * 32];
  __shared__ __align__(16) bf16 Bs[128 * 32];
  const int t = threadIdx.x;
  const int l = t & 63;
  const int w = t >> 6;
  const int q4 = l >> 4;    // quad 0..3
  const int li = l & 15;
  const int m0 = blockIdx.y * 128;
  const int n0 = blockIdx.x * 128;
  const int wr = (w >> 1) * 64;
  const int wc = (w & 1) * 64;

  f32x4 acc[4][4] = {};

  const int colst = (t & 3) * 8;  // staging col within 32-wide tile
  const bf16* gA = A + (size_t)m0 * K;
  const bf16* gB = B + (size_t)n0 * K;

  for (int k0 = 0; k0 < K; k0 += 32) {
#pragma unroll
    for (int p = 0; p < 2; ++p) {
      const int row = p * 64 + (t >> 2);
      const int lbase = p * 2048 + (t & ~63) * 8;
      async_ld16(gA + (size_t)row * K + k0 + colst, &As[lbase]);
      async_ld16(gB + (size_t)row * K + k0 + colst, &Bs[lbase]);
    }
    __syncthreads();
    bf16x8 af[4], bfr[4];
#pragma unroll
    for (int i = 0; i < 4; ++i)
      af[i] = *(const bf16x8*)&As[(wr + i * 16 + li) * 32 + q4 * 8];
#pragma unroll
    for (int j = 0; j < 4; ++j)
      bfr[j] = *(const bf16x8*)&Bs[(wc + j * 16 + li) * 32 + q4 * 8];
#pragma unroll
    for (int i = 0; i < 4; ++i)
#pragma unroll
      for (int j = 0; j < 4; ++j)
        acc[i][j] = MFMA16(af[i], bfr[j], acc[i][j]);
    __syncthreads();
  }

  // epilogue: C/D layout col=li, row=q4*4+r (verified m89/m91)
#pragma unroll
  for (int i = 0; i < 4; ++i) {
#pragma unroll
    for (int j = 0; j < 4; ++j) {
#pragma unroll
      for (int r = 0; r < 4; ++r) {
        const int gm = m0 + wr + i * 16 + q4 * 4 + r;
        const int gn = n0 + wc + j * 16 + li;
        const float v = acc[i][j][r];
        if (MODE == 0) {
          C[(size_t)gm * N + gn] = cvt_out<OT>(v);
        } else if (MODE == 1) {
          const int b = gm >> 11, nn = gm & 2047;
          const int h = gn >> 7, d = gn & 127;
          C[((size_t)(b * 16 + h) * 2048 + nn) * 128 + d] = cvt_out<OT>(v);
        } else {
          const int h = gm >> 7, d = gm & 127;
          const int b = gn >> 11, nn = gn & 2047;
          C[((size_t)(b * 16 + h) * 128 + d) * 2048 + nn] = cvt_out<OT>(v);
        }
      }
    }
  }
}

// ---------------------------------------------------------------------------
// Causal flash attention, S^T formulation.
// qm,km: (BH=32, N=2048, 128) bf16; vtm: (BH, 128, 2048) bf16 (V transposed)
// om: (4096, 2048) = (b*2048+n, h*128+d) bf16
// Block: 256 thr (4 waves); 64 Q rows/block (16 queries per wave, one per
// lane-mod-16); KT=64; scale 1/8.
// S^T = K·Q^T so each lane owns one query column: softmax reduction is
// 15 in-lane ops + 2 cross-quad shuffles; P^T's C-layout (row=q4*4+r) matches
// the K=16 MFMA operand layout (k=q4*4+j) so PV (O^T += V^T·P^T) runs straight
// from registers — no P LDS round trip.
// Grid: (bh=32, 32), qt = 31-blockIdx.y (LPT: long blocks first), 1024 blocks
// = 4/CU (LDS 34 KB, launch_bounds(256,4)).
// ---------------------------------------------------------------------------
#define VSTR 72

__global__ __launch_bounds__(256, 4)
void flash_attn(const bf16* __restrict__ qm, const bf16* __restrict__ km,
                const bf16* __restrict__ vtm, bf16* __restrict__ om) {
  __shared__ __align__(16) bf16 Ks[64 * 128];
  __shared__ __align__(16) bf16 Vts[128 * VSTR];

  const int t = threadIdx.x;
  const int l = t & 63, w = t >> 6;
  const int q4 = l >> 4, li = l & 15;
  const int bh = blockIdx.x;
  const int qt = 31 - (int)blockIdx.y;
  const int qs = qt * 64;
  const size_t qkbase = (size_t)bh * 2048 * 128;
  const size_t vbase = (size_t)bh * 128 * 2048;
  const int b = bh >> 4, h = bh & 15;

  // Q fragments (B operand of S^T): lane holds Q[qs+w*16+li][f*32 + q4*8 + j]
  bf16x8 qf[4];
  const bf16* Qb = qm + qkbase + (size_t)(qs + w * 16) * 128;
#pragma unroll
  for (int f = 0; f < 4; ++f)
    qf[f] = *(const bf16x8*)(Qb + (size_t)li * 128 + f * 32 + q4 * 8);

  f32x4 O[8] = {};                 // O^T: row d = dt*16+q4*4+r, col query li
  float mrun = NEG_BIG, lrun = 0.f;
  const int gm = qs + w * 16 + li; // this lane's absolute query index

  for (int kt = 0; kt <= qt; ++kt) {
    const int kn = kt * 64;
    // stage K (64x128, XOR chunk swizzle) and Vt (128x64, padded stride 72)
#pragma unroll
    for (int p = 0; p < 4; ++p) {
      const int L = p * 256 + t;  // 0..1023
      {
        const int row = L >> 4, c = L & 15;
        *(bf16x8*)&Ks[row * 128 + ((c ^ (row & 7)) * 8)] =
            *(const bf16x8*)(km + qkbase + (size_t)(kn + row) * 128 + c * 8);
      }
      {
        const int row = L >> 3, c = L & 7;
        *(bf16x8*)&Vts[row * VSTR + c * 8] =
            *(const bf16x8*)(vtm + vbase + (size_t)row * 2048 + kn + c * 8);
      }
    }
    __syncthreads();

    // S^T = K Q^T : D[key = jk*16 + q4*4 + r][query = li]
    f32x4 S[4];
#pragma unroll
    for (int jk = 0; jk < 4; ++jk) {
      f32x4 s = {0.f, 0.f, 0.f, 0.f};
#pragma unroll
      for (int f = 0; f < 4; ++f) {
        const bf16x8 kf =
            *(const bf16x8*)&Ks[(jk * 16 + li) * 128 + (((f * 4 + q4) ^ (li & 7)) * 8)];
        s = MFMA16(kf, qf[f], s);
      }
      S[jk] = s;
    }

    // online softmax, one query per lane
    const bool diag = (kt == qt);
    float p[16];
    float mx = NEG_BIG;
#pragma unroll
    for (int jk = 0; jk < 4; ++jk)
#pragma unroll
      for (int r = 0; r < 4; ++r) {
        float sv = S[jk][r] * 0.125f;
        if (diag && (kn + jk * 16 + q4 * 4 + r) > gm) sv = NEG_BIG;
        p[jk * 4 + r] = sv;
        mx = fmaxf(mx, sv);
      }
    mx = fmaxf(mx, __shfl_xor(mx, 16));
    mx = fmaxf(mx, __shfl_xor(mx, 32));
    const float nm = fmaxf(mrun, mx);
    const float alpha = __expf(mrun - nm);
    mrun = nm;
    float rs = 0.f;
#pragma unroll
    for (int i = 0; i < 16; ++i) {
      p[i] = __expf(p[i] - nm);
      rs += p[i];
    }
    rs += __shfl_xor(rs, 16);
    rs += __shfl_xor(rs, 32);
    lrun = lrun * alpha + rs;
#pragma unroll
    for (int dt = 0; dt < 8; ++dt) O[dt] *= alpha;

    // O^T += V^T · P^T  (A = V^T rows d, B = P^T straight from registers)
#if HAVE_MFMA_K16
    bf16x4 pb[4];
#pragma unroll
    for (int kc = 0; kc < 4; ++kc)
#pragma unroll
      for (int j = 0; j < 4; ++j)
        pb[kc][j] = f2bf(p[kc * 4 + j]);
#pragma unroll
    for (int dt = 0; dt < 8; ++dt)
#pragma unroll
      for (int kc = 0; kc < 4; ++kc) {
        const bf16x4 va = *(const bf16x4*)&Vts[(dt * 16 + li) * VSTR + kc * 16 + q4 * 4];
        O[dt] = __builtin_amdgcn_mfma_f32_16x16x16bf16_1k(va, pb[kc], O[dt], 0, 0, 0);
      }
#else
    // fallback: zero-padded K=32 MFMA (upper half of contraction is zeros on
    // both operands, so the extra terms vanish)
    bf16x8 pb[4];
#pragma unroll
    for (int kc = 0; kc < 4; ++kc) {
#pragma unroll
      for (int j = 0; j < 4; ++j) pb[kc][j] = f2bf(p[kc * 4 + j]);
#pragma unroll
      for (int j = 4; j < 8; ++j) pb[kc][j] = 0;
    }
#pragma unroll
    for (int dt = 0; dt < 8; ++dt)
#pragma unroll
      for (int kc = 0; kc < 4; ++kc) {
        const bf16x4 v4 = *(const bf16x4*)&Vts[(dt * 16 + li) * VSTR + kc * 16 + q4 * 4];
        const bf16x8 va = {v4[0], v4[1], v4[2], v4[3], 0, 0, 0, 0};
        O[dt] = MFMA16(va, pb[kc], O[dt]);
      }
#endif
    __syncthreads();
  }

  // epilogue: normalize, write om[query][h*128 + d], d = dt*16 + q4*4 + r
  const float inv = 1.0f / lrun;
  const size_t orow = (size_t)(b * 2048 + qs + w * 16 + li) * 2048 + h * 128;
#pragma unroll
  for (int dt = 0; dt < 8; ++dt) {
    bf16x4 o4;
#pragma unroll
    for (int r = 0; r < 4; ++r) o4[r] = f2bf(O[dt][r] * inv);
    *(bf16x4*)&om[orow + dt * 16 + q4 * 4] = o4;
  }
}

// ---------------------------------------------------------------------------
extern "C" void kernel_launch(void* const* d_in, const int* in_sizes, int n_in,
                              void* d_out, int out_size, void* d_ws, size_t ws_size,
                              hipStream_t stream) {
  // Reference dtypes are float32 (inputs AND output).
  const float* x = (const float*)d_in[0];
  const float* Wq = (const float*)d_in[1];
  const float* Wk = (const float*)d_in[2];
  const float* Wv = (const float*)d_in[3];
  const float* Wo = (const float*)d_in[4];
  float* out = (float*)d_out;

  // Workspace layout (bf16 elems), 36M elems = 72 MB total:
  //   [0,4M)   xb           (x in bf16)
  //   [4M,6M)  wTq          (Wq^T)
  //   [6M,8M)  wTk
  //   [8M,10M) wTv
  //   [10M,12M) woT         (Wo^T, survives until final GEMM)
  //   [12M,20M) q_ws  (b,h,n,d)
  //   [20M,28M) k_ws  (b,h,n,d)
  //   [28M,36M) vt_ws (b,h,d,n)
  //   at_ws = [2M,10M): aliases xb upper half + wTq/wTk/wTv, all dead after
  //   the V GEMM and before flash_attn writes it.
  bf16* ws = (bf16*)d_ws;
  const size_t MEG = 1u << 20;
  bf16* xb = ws;
  bf16* wTq = ws + 4 * MEG;
  bf16* wTk = ws + 6 * MEG;
  bf16* wTv = ws + 8 * MEG;
  bf16* woT = ws + 10 * MEG;
  bf16* at_ws = ws + 2 * MEG;
  bf16* q_ws = ws + 12 * MEG;
  bf16* k_ws = ws + 20 * MEG;
  bf16* vt_ws = ws + 28 * MEG;

  const dim3 blk(256);

  // x -> bf16  (4096*1024 = 2^22 elems, 4/thread)
  convert_f32_bf16<<<dim3(4096), blk, 0, stream>>>(x, xb, 1 << 20);
  // all four weight transposes in one dispatch
  transpose4_f32_bf16<<<dim3(64, 32, 4), blk, 0, stream>>>(Wq, Wk, Wv, Wo,
                                                           wTq, wTk, wTv, woT);
  // Q = x @ Wq  -> (b,h,n,d)
  gemm_bt<1, bf16><<<dim3(16, 32), blk, 0, stream>>>(xb, wTq, q_ws, 4096, 2048, 1024);
  // K = x @ Wk  -> (b,h,n,d)
  gemm_bt<1, bf16><<<dim3(16, 32), blk, 0, stream>>>(xb, wTk, k_ws, 4096, 2048, 1024);
  // V^T = WvT @ x^T -> (b,h,d,n)
  gemm_bt<2, bf16><<<dim3(32, 16), blk, 0, stream>>>(wTv, xb, vt_ws, 2048, 4096, 1024);
  // attention (grid: bh x qt, LPT order inside kernel)
  flash_attn<<<dim3(32, 32), blk, 0, stream>>>(q_ws, k_ws, vt_ws, at_ws);
  // out = attn @ Wo  (f32 output)
  gemm_bt<0, float><<<dim3(8, 32), blk, 0, stream>>>(at_ws, woT, out, 4096, 1024, 2048);
}

// Round 6
// 276.894 us; speedup vs baseline: 1.5045x; 1.1333x over previous
//
#include <hip/hip_runtime.h>
#include <hip/hip_bf16.h>
#include <stdint.h>
#include <cmath>

using bf16 = __hip_bfloat16;
typedef __attribute__((ext_vector_type(8))) short bf16x8;
typedef __attribute__((ext_vector_type(4))) short bf16x4;
typedef __attribute__((ext_vector_type(4))) float f32x4;

#define MFMA16(a, b, c) __builtin_amdgcn_mfma_f32_16x16x32_bf16(a, b, c, 0, 0, 0)

#if defined(__has_builtin)
#if __has_builtin(__builtin_amdgcn_mfma_f32_16x16x16bf16_1k)
#define HAVE_MFMA_K16 1
#endif
#endif
#ifndef HAVE_MFMA_K16
#define HAVE_MFMA_K16 0
#endif

#define NEG_BIG (-1e30f)

__device__ __forceinline__ short f2bf(float v) {
  return __builtin_bit_cast(short, __float2bfloat16(v));
}

// K=16 bf16 MFMA (A,B = 4 bf16/lane). Fallback: zero-padded K=32.
__device__ __forceinline__ f32x4 pv_mfma(bf16x4 va, bf16x4 pb, f32x4 c) {
#if HAVE_MFMA_K16
  return __builtin_amdgcn_mfma_f32_16x16x16bf16_1k(va, pb, c, 0, 0, 0);
#else
  const bf16x8 a = {va[0], va[1], va[2], va[3], 0, 0, 0, 0};
  const bf16x8 b = {pb[0], pb[1], pb[2], pb[3], 0, 0, 0, 0};
  return MFMA16(a, b, c);
#endif
}

// async global->LDS, 16B per lane. LDS dest = wave-uniform base + lane*16.
__device__ __forceinline__ void async_ld16(const bf16* g, bf16* l) {
  __builtin_amdgcn_global_load_lds(
      (const __attribute__((address_space(1))) unsigned int*)g,
      (__attribute__((address_space(3))) unsigned int*)l, 16, 0, 0);
}

template <typename T> __device__ __forceinline__ T cvt_out(float v);
template <> __device__ __forceinline__ float cvt_out<float>(float v) { return v; }
template <> __device__ __forceinline__ bf16 cvt_out<bf16>(float v) { return __float2bfloat16(v); }

// ---------------------------------------------------------------------------
// prep: one dispatch = x f32->bf16 convert + all four weight transposes.
// bid < 8192: transpose tile (z = bid>>11: Wq/Wk/Wv are 1024x2048, Wo 2048x1024)
// bid >= 8192: convert chunk (4096 blocks x 256 thr x 1 float4)
// ---------------------------------------------------------------------------
__global__ void prep(const float* __restrict__ x,
                     const float* __restrict__ Wq, const float* __restrict__ Wk,
                     const float* __restrict__ Wv, const float* __restrict__ Wo,
                     bf16* __restrict__ xb, bf16* __restrict__ tq,
                     bf16* __restrict__ tk, bf16* __restrict__ tv,
                     bf16* __restrict__ to_) {
  __shared__ bf16 tile[32][33];
  const int bid = blockIdx.x;
  if (bid < 8192) {
    const int z = bid >> 11, tt = bid & 2047;
    const float* in = z == 0 ? Wq : z == 1 ? Wk : z == 2 ? Wv : Wo;
    bf16* out = z == 0 ? tq : z == 1 ? tk : z == 2 ? tv : to_;
    int R, Cc, c0, r0;
    if (z < 3) { R = 1024; Cc = 2048; c0 = (tt & 63) * 32; r0 = (tt >> 6) * 32; }
    else       { R = 2048; Cc = 1024; c0 = (tt & 31) * 32; r0 = (tt >> 5) * 32; }
    const int xx = threadIdx.x & 31;
    const int y = threadIdx.x >> 5;
#pragma unroll
    for (int yy = y; yy < 32; yy += 8)
      tile[yy][xx] = __float2bfloat16(in[(size_t)(r0 + yy) * Cc + c0 + xx]);
    __syncthreads();
#pragma unroll
    for (int yy = y; yy < 32; yy += 8)
      out[(size_t)(c0 + yy) * R + r0 + xx] = tile[xx][yy];
  } else {
    const int i = (bid - 8192) * 256 + threadIdx.x;  // < 1<<20 float4s
    const float4 v = ((const float4*)x)[i];
    bf16 o[4] = {__float2bfloat16(v.x), __float2bfloat16(v.y),
                 __float2bfloat16(v.z), __float2bfloat16(v.w)};
    *(uint64_t*)&xb[i * 4] = *(const uint64_t*)o;
  }
}

// ---------------------------------------------------------------------------
// Fused QKV projection: one dispatch, grid (512, 3).
// op=0: Q = xb @ WqT  -> (b,h,n,d)     (A=xb 4096xK, B=wq 2048xK)
// op=1: K = xb @ WkT  -> (b,h,n,d)
// op=2: V^T = wv @ xb^T -> (b,h,d,n)   (A=wv 2048xK, B=xb 4096xK)
// 128x128 tile, BK=32, 256 threads; m97 structure (global_load_lds w=16).
// ---------------------------------------------------------------------------
__global__ __launch_bounds__(256)
void gemm_qkv(const bf16* __restrict__ xb, const bf16* __restrict__ wq,
              const bf16* __restrict__ wk, const bf16* __restrict__ wv,
              bf16* __restrict__ qo, bf16* __restrict__ ko, bf16* __restrict__ vo) {
  __shared__ __align__(16) bf16 As[128 * 32];
  __shared__ __align__(16) bf16 Bs[128 * 32];
  const int op = blockIdx.y;
  const int bid = blockIdx.x;
  const bf16 *A, *B;
  int m0, n0;
  if (op < 2) { A = xb; B = op ? wk : wq; m0 = (bid >> 4) * 128; n0 = (bid & 15) * 128; }
  else        { A = wv; B = xb;           m0 = (bid & 15) * 128; n0 = (bid >> 4) * 128; }
  const int K = 1024;

  const int t = threadIdx.x;
  const int l = t & 63, w = t >> 6;
  const int q4 = l >> 4, li = l & 15;
  const int wr = (w >> 1) * 64, wc = (w & 1) * 64;

  f32x4 acc[4][4] = {};
  const int colst = (t & 3) * 8;
  const bf16* gA = A + (size_t)m0 * K;
  const bf16* gB = B + (size_t)n0 * K;

  for (int k0 = 0; k0 < K; k0 += 32) {
#pragma unroll
    for (int p = 0; p < 2; ++p) {
      const int row = p * 64 + (t >> 2);
      const int lbase = p * 2048 + (t & ~63) * 8;
      async_ld16(gA + (size_t)row * K + k0 + colst, &As[lbase]);
      async_ld16(gB + (size_t)row * K + k0 + colst, &Bs[lbase]);
    }
    __syncthreads();
    bf16x8 af[4], bfr[4];
#pragma unroll
    for (int i = 0; i < 4; ++i)
      af[i] = *(const bf16x8*)&As[(wr + i * 16 + li) * 32 + q4 * 8];
#pragma unroll
    for (int j = 0; j < 4; ++j)
      bfr[j] = *(const bf16x8*)&Bs[(wc + j * 16 + li) * 32 + q4 * 8];
#pragma unroll
    for (int i = 0; i < 4; ++i)
#pragma unroll
      for (int j = 0; j < 4; ++j)
        acc[i][j] = MFMA16(af[i], bfr[j], acc[i][j]);
    __syncthreads();
  }

#pragma unroll
  for (int i = 0; i < 4; ++i)
#pragma unroll
    for (int j = 0; j < 4; ++j)
#pragma unroll
      for (int r = 0; r < 4; ++r) {
        const int gm = m0 + wr + i * 16 + q4 * 4 + r;
        const int gn = n0 + wc + j * 16 + li;
        const bf16 v = __float2bfloat16(acc[i][j][r]);
        if (op < 2) {  // (b,h,n,d): m=b*2048+n, col=h*128+d
          const int b = gm >> 11, nn = gm & 2047;
          const int h = gn >> 7, d = gn & 127;
          (op ? ko : qo)[((size_t)(b * 16 + h) * 2048 + nn) * 128 + d] = v;
        } else {       // (b,h,d,n): m=h*128+d, col=b*2048+n
          const int h = gm >> 7, d = gm & 127;
          const int b = gn >> 11, nn = gn & 2047;
          vo[((size_t)(b * 16 + h) * 128 + d) * 2048 + nn] = v;
        }
      }
}

// ---------------------------------------------------------------------------
// GEMM-BT (final projection): C[m][n] = sum_k A[m][k]*B[n][k], C row-major f32.
// 128xNT tile (NT=64 -> 512 blocks at N=1024), BK=32, 256 threads.
// ---------------------------------------------------------------------------
template <int NT, typename OT>
__global__ __launch_bounds__(256)
void gemm_bt(const bf16* __restrict__ A, const bf16* __restrict__ B,
             OT* __restrict__ C, int M, int N, int K) {
  __shared__ __align__(16) bf16 As[128 * 32];
  __shared__ __align__(16) bf16 Bs[NT * 32];
  constexpr int JN = NT / 32;  // acc cols per wave
  const int t = threadIdx.x;
  const int l = t & 63, w = t >> 6;
  const int q4 = l >> 4, li = l & 15;
  const int m0 = blockIdx.y * 128;
  const int n0 = blockIdx.x * NT;
  const int wr = (w >> 1) * 64, wc = (w & 1) * (NT / 2);

  f32x4 acc[4][JN] = {};
  const int colst = (t & 3) * 8;
  const bf16* gA = A + (size_t)m0 * K;
  const bf16* gB = B + (size_t)n0 * K;

  for (int k0 = 0; k0 < K; k0 += 32) {
#pragma unroll
    for (int p = 0; p < 2; ++p) {
      const int row = p * 64 + (t >> 2);
      const int lbase = p * 2048 + (t & ~63) * 8;
      async_ld16(gA + (size_t)row * K + k0 + colst, &As[lbase]);
    }
#pragma unroll
    for (int p = 0; p < NT / 64; ++p) {
      const int row = p * 64 + (t >> 2);
      const int lbase = p * 2048 + (t & ~63) * 8;
      async_ld16(gB + (size_t)row * K + k0 + colst, &Bs[lbase]);
    }
    __syncthreads();
    bf16x8 af[4], bfr[JN];
#pragma unroll
    for (int i = 0; i < 4; ++i)
      af[i] = *(const bf16x8*)&As[(wr + i * 16 + li) * 32 + q4 * 8];
#pragma unroll
    for (int j = 0; j < JN; ++j)
      bfr[j] = *(const bf16x8*)&Bs[(wc + j * 16 + li) * 32 + q4 * 8];
#pragma unroll
    for (int i = 0; i < 4; ++i)
#pragma unroll
      for (int j = 0; j < JN; ++j)
        acc[i][j] = MFMA16(af[i], bfr[j], acc[i][j]);
    __syncthreads();
  }

#pragma unroll
  for (int i = 0; i < 4; ++i)
#pragma unroll
    for (int j = 0; j < JN; ++j)
#pragma unroll
      for (int r = 0; r < 4; ++r) {
        const int gm = m0 + wr + i * 16 + q4 * 4 + r;
        const int gn = n0 + wc + j * 16 + li;
        C[(size_t)gm * N + gn] = cvt_out<OT>(acc[i][j][r]);
      }
}

// ---------------------------------------------------------------------------
// Causal flash attention, S^T formulation, QT=128 queries/block.
// qm,km: (BH=32, 2048, 128) bf16; vtm: (BH, 128, 2048) bf16 (V transposed)
// om: (4096, 2048) = (b*2048+n, h*128+d) bf16
// 4 waves; each wave owns 32 queries as 2 column groups of 16 (one query per
// lane-mod-16). KT=64. K/Vt staged once per tile, fragments shared across
// both column groups (2x arithmetic intensity per LDS byte vs QT=64).
// Softmax: per-lane over 16 keys + 2 cross-quad shuffles; exp packs straight
// to bf16 pb (P never stored). PV: O^T += V^T P^T via K=16 MFMA from regs.
// Grid (32 bh, 16): y<8 -> qt=15-y (long first), else qt=y-8, so the two
// blocks co-resident on a CU sum to ~34 K-tiles (balance heuristic).
// ---------------------------------------------------------------------------
#define VSTR 72

__global__ __launch_bounds__(256, 2)
void flash_attn(const bf16* __restrict__ qm, const bf16* __restrict__ km,
                const bf16* __restrict__ vtm, bf16* __restrict__ om) {
  __shared__ __align__(16) bf16 Ks[64 * 128];
  __shared__ __align__(16) bf16 Vts[128 * VSTR];

  const int t = threadIdx.x;
  const int l = t & 63, w = t >> 6;
  const int q4 = l >> 4, li = l & 15;
  const int bh = blockIdx.x;
  const int y = blockIdx.y;
  const int qt = (y < 8) ? 15 - y : y - 8;
  const int qs = qt * 128;
  const size_t qkbase = (size_t)bh * 2048 * 128;
  const size_t vbase = (size_t)bh * 128 * 2048;
  const int b = bh >> 4, h = bh & 15;

  // Q fragments (B operand of S^T) for both column groups
  bf16x8 qf[2][4];
#pragma unroll
  for (int g = 0; g < 2; ++g) {
    const bf16* Qb = qm + qkbase + (size_t)(qs + w * 32 + g * 16 + li) * 128;
#pragma unroll
    for (int f = 0; f < 4; ++f)
      qf[g][f] = *(const bf16x8*)(Qb + f * 32 + q4 * 8);
  }

  f32x4 O[2][8] = {};
  float mrun[2] = {NEG_BIG, NEG_BIG}, lrun[2] = {0.f, 0.f};
  const int gmq[2] = {qs + w * 32 + li, qs + w * 32 + 16 + li};

  const int ktmax = 2 * qt + 1;
  for (int kt = 0; kt <= ktmax; ++kt) {
    const int kn = kt * 64;
    // stage K (64x128, XOR chunk swizzle) and Vt (128x64, padded stride 72)
#pragma unroll
    for (int p = 0; p < 4; ++p) {
      const int L = p * 256 + t;
      {
        const int row = L >> 4, c = L & 15;
        *(bf16x8*)&Ks[row * 128 + ((c ^ (row & 7)) * 8)] =
            *(const bf16x8*)(km + qkbase + (size_t)(kn + row) * 128 + c * 8);
      }
      {
        const int row = L >> 3, c = L & 7;
        *(bf16x8*)&Vts[row * VSTR + c * 8] =
            *(const bf16x8*)(vtm + vbase + (size_t)row * 2048 + kn + c * 8);
      }
    }
    __syncthreads();

    // S^T = K Q^T : S[g][jk] reg r = score(key = jk*16+q4*4+r, query = li)
    f32x4 S[2][4];
#pragma unroll
    for (int jk = 0; jk < 4; ++jk) {
      bf16x8 kf[4];
#pragma unroll
      for (int f = 0; f < 4; ++f)
        kf[f] = *(const bf16x8*)&Ks[(jk * 16 + li) * 128 + (((f * 4 + q4) ^ (li & 7)) * 8)];
#pragma unroll
      for (int g = 0; g < 2; ++g) {
        f32x4 s = {0.f, 0.f, 0.f, 0.f};
#pragma unroll
        for (int f = 0; f < 4; ++f) s = MFMA16(kf[f], qf[g][f], s);
        S[g][jk] = s;
      }
    }

    // online softmax per group; exp packs straight into bf16 pb
    bf16x4 pb[2][4];
#pragma unroll
    for (int g = 0; g < 2; ++g) {
      const bool needmask = (kn + 63) > (qs + w * 32 + g * 16);
      float pv[16];
      float mx = NEG_BIG;
#pragma unroll
      for (int jk = 0; jk < 4; ++jk)
#pragma unroll
        for (int r = 0; r < 4; ++r) {
          float sv = S[g][jk][r] * 0.125f;
          if (needmask && (kn + jk * 16 + q4 * 4 + r) > gmq[g]) sv = NEG_BIG;
          pv[jk * 4 + r] = sv;
          mx = fmaxf(mx, sv);
        }
      mx = fmaxf(mx, __shfl_xor(mx, 16));
      mx = fmaxf(mx, __shfl_xor(mx, 32));
      const float nm = fmaxf(mrun[g], mx);
      const float alpha = __expf(mrun[g] - nm);
      mrun[g] = nm;
      float rs = 0.f;
#pragma unroll
      for (int jk = 0; jk < 4; ++jk)
#pragma unroll
        for (int r = 0; r < 4; ++r) {
          const float e = __expf(pv[jk * 4 + r] - nm);
          rs += e;
          pb[g][jk][r] = f2bf(e);
        }
      rs += __shfl_xor(rs, 16);
      rs += __shfl_xor(rs, 32);
      lrun[g] = lrun[g] * alpha + rs;
#pragma unroll
      for (int dt = 0; dt < 8; ++dt) O[g][dt] *= alpha;
    }

    // O^T += V^T P^T : va read once, used by both groups
#pragma unroll
    for (int dt = 0; dt < 8; ++dt)
#pragma unroll
      for (int kc = 0; kc < 4; ++kc) {
        const bf16x4 va = *(const bf16x4*)&Vts[(dt * 16 + li) * VSTR + kc * 16 + q4 * 4];
        O[0][dt] = pv_mfma(va, pb[0][kc], O[0][dt]);
        O[1][dt] = pv_mfma(va, pb[1][kc], O[1][dt]);
      }
    __syncthreads();
  }

  // epilogue: normalize, write om[query][h*128+d], d = dt*16+q4*4+r
#pragma unroll
  for (int g = 0; g < 2; ++g) {
    const float inv = 1.0f / lrun[g];
    const size_t orow = (size_t)(b * 2048 + qs + w * 32 + g * 16 + li) * 2048 + h * 128;
#pragma unroll
    for (int dt = 0; dt < 8; ++dt) {
      bf16x4 o4;
#pragma unroll
      for (int r = 0; r < 4; ++r) o4[r] = f2bf(O[g][dt][r] * inv);
      *(bf16x4*)&om[orow + dt * 16 + q4 * 4] = o4;
    }
  }
}

// ---------------------------------------------------------------------------
extern "C" void kernel_launch(void* const* d_in, const int* in_sizes, int n_in,
                              void* d_out, int out_size, void* d_ws, size_t ws_size,
                              hipStream_t stream) {
  const float* x = (const float*)d_in[0];
  const float* Wq = (const float*)d_in[1];
  const float* Wk = (const float*)d_in[2];
  const float* Wv = (const float*)d_in[3];
  const float* Wo = (const float*)d_in[4];
  float* out = (float*)d_out;

  // Workspace (bf16 elems), 36M = 72 MB:
  //   [0,4M) xb | [4M,6M) wTq | [6M,8M) wTk | [8M,10M) wTv | [10M,12M) woT
  //   [12M,20M) q_ws | [20M,28M) k_ws | [28M,36M) vt_ws
  //   at_ws = [2M,10M) (aliases xb-upper + wTq/k/v; dead before flash writes)
  bf16* ws = (bf16*)d_ws;
  const size_t MEG = 1u << 20;
  bf16* xb = ws;
  bf16* wTq = ws + 4 * MEG;
  bf16* wTk = ws + 6 * MEG;
  bf16* wTv = ws + 8 * MEG;
  bf16* woT = ws + 10 * MEG;
  bf16* at_ws = ws + 2 * MEG;
  bf16* q_ws = ws + 12 * MEG;
  bf16* k_ws = ws + 20 * MEG;
  bf16* vt_ws = ws + 28 * MEG;

  const dim3 blk(256);

  prep<<<dim3(12288), blk, 0, stream>>>(x, Wq, Wk, Wv, Wo, xb, wTq, wTk, wTv, woT);
  gemm_qkv<<<dim3(512, 3), blk, 0, stream>>>(xb, wTq, wTk, wTv, q_ws, k_ws, vt_ws);
  flash_attn<<<dim3(32, 16), blk, 0, stream>>>(q_ws, k_ws, vt_ws, at_ws);
  gemm_bt<64, float><<<dim3(16, 32), blk, 0, stream>>>(at_ws, woT, out, 4096, 1024, 2048);
}